// Round 1
// baseline (23994.760 us; speedup 1.0000x reference)
//
#include <hip/hip_runtime.h>
#include <hip/hip_bf16.h>
#include <math.h>

// Problem constants (match reference)
constexpr int B_  = 2;
constexpr int S_  = 1024;
constexpr int E_  = 1024;   // = NH*AH
constexpr int NH_ = 16;
constexpr int AH_ = 64;
constexpr int NL_ = 4;
constexpr int HC_ = 2048;
constexpr int V_  = 32000;
constexpr int T_  = B_ * S_;          // 2048 token rows
constexpr int EE_ = E_ * E_;          // per-layer weight stride

// ---------------------------------------------------------------------------
// x + positional encoding.  PE computed on the fly in fp64 to mirror numpy's
// float64 10000**(k/E) path (sin/cos arg up to ~1023 — fp64 keeps phase exact).
// ---------------------------------------------------------------------------
__global__ __launch_bounds__(256) void add_pe_kernel(const float* __restrict__ in,
                                                     float* __restrict__ out,
                                                     int total) {
  int idx = blockIdx.x * 256 + threadIdx.x;
  if (idx >= total) return;
  int e = idx & (E_ - 1);
  int s = (idx >> 10) & (S_ - 1);        // E_=1024
  double arg = (double)s * exp(-(double)(e >> 1) * (9.210340371976184 / (double)E_));
  float pe = (e & 1) ? (float)cos(arg) : (float)sin(arg);
  out[idx] = in[idx] + pe;
}

// ---------------------------------------------------------------------------
// fp32 tiled GEMM: C[M,N] = A[M,K] @ B[K,N] (+bias) (+relu)
// 64x64 block tile, K-tile 16, 256 threads, 4x4 per thread.
// All M,N,K used here are multiples of 64 -> no bounds checks.
// ---------------------------------------------------------------------------
__global__ __launch_bounds__(256) void gemm_f32(const float* __restrict__ A,
                                                const float* __restrict__ Bm,
                                                const float* __restrict__ bias,
                                                float* __restrict__ C,
                                                int M, int N, int K, int relu) {
  __shared__ float As[16][65];   // As[k][m], +1 pad
  __shared__ float Bs[16][64];   // Bs[k][n]

  const int tid = threadIdx.x;
  const int tx = tid & 15;       // 0..15 -> 4 cols each
  const int ty = tid >> 4;       // 0..15 -> 4 rows each
  const int m0 = blockIdx.y * 64;
  const int n0 = blockIdx.x * 64;

  // A-load mapping: one float4 per thread: row am, cols ak4..ak4+3
  const int am  = tid >> 2;            // 0..63
  const int ak4 = (tid & 3) << 2;      // 0,4,8,12
  // B-load mapping: 4 rows per thread, coalesced cols
  const int brow = tid >> 6;           // 0..3
  const int bcol = tid & 63;           // 0..63

  float acc[4][4];
#pragma unroll
  for (int i = 0; i < 4; ++i)
#pragma unroll
    for (int j = 0; j < 4; ++j) acc[i][j] = 0.f;

  for (int k0 = 0; k0 < K; k0 += 16) {
    float4 av = *(const float4*)&A[(size_t)(m0 + am) * K + k0 + ak4];
    As[ak4 + 0][am] = av.x;
    As[ak4 + 1][am] = av.y;
    As[ak4 + 2][am] = av.z;
    As[ak4 + 3][am] = av.w;
#pragma unroll
    for (int r = 0; r < 4; ++r) {
      Bs[brow + 4 * r][bcol] = Bm[(size_t)(k0 + brow + 4 * r) * N + n0 + bcol];
    }
    __syncthreads();
#pragma unroll
    for (int kk = 0; kk < 16; ++kk) {
      float a0 = As[kk][ty * 4 + 0];
      float a1 = As[kk][ty * 4 + 1];
      float a2 = As[kk][ty * 4 + 2];
      float a3 = As[kk][ty * 4 + 3];
      float b0 = Bs[kk][tx * 4 + 0];
      float b1 = Bs[kk][tx * 4 + 1];
      float b2 = Bs[kk][tx * 4 + 2];
      float b3 = Bs[kk][tx * 4 + 3];
      acc[0][0] += a0 * b0; acc[0][1] += a0 * b1; acc[0][2] += a0 * b2; acc[0][3] += a0 * b3;
      acc[1][0] += a1 * b0; acc[1][1] += a1 * b1; acc[1][2] += a1 * b2; acc[1][3] += a1 * b3;
      acc[2][0] += a2 * b0; acc[2][1] += a2 * b1; acc[2][2] += a2 * b2; acc[2][3] += a2 * b3;
      acc[3][0] += a3 * b0; acc[3][1] += a3 * b1; acc[3][2] += a3 * b2; acc[3][3] += a3 * b3;
    }
    __syncthreads();
  }

#pragma unroll
  for (int i = 0; i < 4; ++i) {
    float4 o;
    float bx = 0.f, by = 0.f, bz = 0.f, bw = 0.f;
    if (bias) {
      bx = bias[n0 + tx * 4 + 0];
      by = bias[n0 + tx * 4 + 1];
      bz = bias[n0 + tx * 4 + 2];
      bw = bias[n0 + tx * 4 + 3];
    }
    o.x = acc[i][0] + bx;
    o.y = acc[i][1] + by;
    o.z = acc[i][2] + bz;
    o.w = acc[i][3] + bw;
    if (relu) {
      o.x = fmaxf(o.x, 0.f); o.y = fmaxf(o.y, 0.f);
      o.z = fmaxf(o.z, 0.f); o.w = fmaxf(o.w, 0.f);
    }
    *(float4*)&C[(size_t)(m0 + ty * 4 + i) * N + n0 + tx * 4] = o;
  }
}

// ---------------------------------------------------------------------------
// Fused attention: one wave (64 lanes) per (b, h, query row).
// Q,K,V,O layout: [b, s, h*AH + d] (row stride E_).  S fixed at 1024.
// Phase 1: each lane dots q against 16 keys (j = t*64+lane) -> scores in regs.
// Softmax via wave shuffles.  P staged to LDS.
// Phase 2: lane owns output dim d=lane; loops keys with coalesced V loads.
// ---------------------------------------------------------------------------
__global__ __launch_bounds__(256) void attn_kernel(const float* __restrict__ Q,
                                                   const float* __restrict__ Kp,
                                                   const float* __restrict__ Vp,
                                                   float* __restrict__ O,
                                                   int causal) {
  __shared__ float qs[4][64];
  __shared__ float ps[4][S_];

  const int lane = threadIdx.x & 63;
  const int wv   = threadIdx.x >> 6;
  const int w    = blockIdx.x * 4 + wv;
  const int row  = w & (S_ - 1);
  const int h    = (w >> 10) & (NH_ - 1);
  const int b    = w >> 14;   // / (S_*NH_)
  const float scale = 0.125f; // 1/sqrt(64)

  const size_t qoff  = ((size_t)(b * S_ + row)) * E_ + h * AH_;
  const size_t kbase = ((size_t)b * S_) * E_ + h * AH_;

  qs[wv][lane] = Q[qoff + lane];
  __syncthreads();

  // ---- phase 1: scores ----
  float s[16];
  float mx = -3.0e38f;
#pragma unroll 4
  for (int t = 0; t < 16; ++t) {
    const int j = t * 64 + lane;
    const float* kr = Kp + kbase + (size_t)j * E_;
    float dot = 0.f;
#pragma unroll
    for (int d4 = 0; d4 < 64; d4 += 4) {
      float4 kv = *(const float4*)&kr[d4];
      dot += qs[wv][d4 + 0] * kv.x;
      dot += qs[wv][d4 + 1] * kv.y;
      dot += qs[wv][d4 + 2] * kv.z;
      dot += qs[wv][d4 + 3] * kv.w;
    }
    float sc = dot * scale;
    if (causal && j > row) sc = -1.0e9f;   // matches reference mask add
    s[t] = sc;
    mx = fmaxf(mx, sc);
  }
#pragma unroll
  for (int off = 32; off; off >>= 1) mx = fmaxf(mx, __shfl_xor(mx, off, 64));

  float sum = 0.f;
#pragma unroll
  for (int t = 0; t < 16; ++t) {
    float p = expf(s[t] - mx);   // masked entries underflow to exactly 0
    sum += p;
    ps[wv][t * 64 + lane] = p;
  }
#pragma unroll
  for (int off = 32; off; off >>= 1) sum += __shfl_xor(sum, off, 64);
  const float inv = 1.0f / sum;
  __syncthreads();

  // ---- phase 2: PV, lane owns output dim d = lane ----
  const float* vr = Vp + kbase + lane;
  const int jend = causal ? row : (S_ - 1);
  float acc = 0.f;
  int j = 0;
  for (; j + 3 <= jend; j += 4) {
    acc += ps[wv][j + 0] * vr[(size_t)(j + 0) * E_];
    acc += ps[wv][j + 1] * vr[(size_t)(j + 1) * E_];
    acc += ps[wv][j + 2] * vr[(size_t)(j + 2) * E_];
    acc += ps[wv][j + 3] * vr[(size_t)(j + 3) * E_];
  }
  for (; j <= jend; ++j) acc += ps[wv][j] * vr[(size_t)j * E_];

  O[qoff + lane] = acc * inv;
}

// ---------------------------------------------------------------------------
// out[row] = LayerNorm(X[row] + R[row]) * g + b      (row length E_=1024)
// One 256-thread block per row; in-place safe (out may alias R or X).
// ---------------------------------------------------------------------------
__global__ __launch_bounds__(256) void add_ln_kernel(const float* __restrict__ X,
                                                     const float* __restrict__ R,
                                                     const float* __restrict__ g,
                                                     const float* __restrict__ bta,
                                                     float* __restrict__ out) {
  __shared__ float s1[4], s2[4];
  const int row = blockIdx.x;
  const int tid = threadIdx.x;
  const size_t base = (size_t)row * E_;
  const int e = tid * 4;

  float4 xv = *(const float4*)&X[base + e];
  float4 rv = *(const float4*)&R[base + e];
  float v0 = xv.x + rv.x, v1 = xv.y + rv.y, v2 = xv.z + rv.z, v3 = xv.w + rv.w;

  float sum = v0 + v1 + v2 + v3;
  float sq  = v0 * v0 + v1 * v1 + v2 * v2 + v3 * v3;
#pragma unroll
  for (int off = 32; off; off >>= 1) {
    sum += __shfl_xor(sum, off, 64);
    sq  += __shfl_xor(sq,  off, 64);
  }
  if ((tid & 63) == 0) { s1[tid >> 6] = sum; s2[tid >> 6] = sq; }
  __syncthreads();
  sum = s1[0] + s1[1] + s1[2] + s1[3];
  sq  = s2[0] + s2[1] + s2[2] + s2[3];

  const float mean = sum * (1.0f / E_);
  const float var  = sq * (1.0f / E_) - mean * mean;
  const float rs   = rsqrtf(var + 1e-5f);

  float4 gv = *(const float4*)&g[e];
  float4 bv = *(const float4*)&bta[e];
  float4 o;
  o.x = (v0 - mean) * rs * gv.x + bv.x;
  o.y = (v1 - mean) * rs * gv.y + bv.y;
  o.z = (v2 - mean) * rs * gv.z + bv.z;
  o.w = (v3 - mean) * rs * gv.w + bv.w;
  *(float4*)&out[base + e] = o;
}

// ---------------------------------------------------------------------------
extern "C" void kernel_launch(void* const* d_in, const int* in_sizes, int n_in,
                              void* d_out, int out_size, void* d_ws, size_t ws_size,
                              hipStream_t stream) {
  const float* x       = (const float*)d_in[0];
  const float* y       = (const float*)d_in[1];
  const float* enc_wq  = (const float*)d_in[2];
  const float* enc_wk  = (const float*)d_in[3];
  const float* enc_wv  = (const float*)d_in[4];
  const float* enc_wo  = (const float*)d_in[5];
  const float* enc_bo  = (const float*)d_in[6];
  const float* enc_ln1g = (const float*)d_in[7];
  const float* enc_ln1b = (const float*)d_in[8];
  const float* enc_ln2g = (const float*)d_in[9];
  const float* enc_ln2b = (const float*)d_in[10];
  const float* enc_f1w = (const float*)d_in[11];
  const float* enc_f1b = (const float*)d_in[12];
  const float* enc_f2w = (const float*)d_in[13];
  const float* enc_f2b = (const float*)d_in[14];
  const float* dec_wq1 = (const float*)d_in[15];
  const float* dec_wk1 = (const float*)d_in[16];
  const float* dec_wv1 = (const float*)d_in[17];
  const float* dec_wo1 = (const float*)d_in[18];
  const float* dec_bo1 = (const float*)d_in[19];
  const float* dec_wq2 = (const float*)d_in[20];
  const float* dec_wk2 = (const float*)d_in[21];
  const float* dec_wv2 = (const float*)d_in[22];
  const float* dec_wo2 = (const float*)d_in[23];
  const float* dec_bo2 = (const float*)d_in[24];
  const float* dec_ln1g = (const float*)d_in[25];
  const float* dec_ln1b = (const float*)d_in[26];
  const float* dec_ln2g = (const float*)d_in[27];
  const float* dec_ln2b = (const float*)d_in[28];
  const float* dec_ln3g = (const float*)d_in[29];
  const float* dec_ln3b = (const float*)d_in[30];
  const float* dec_f1w = (const float*)d_in[31];
  const float* dec_f1b = (const float*)d_in[32];
  const float* dec_f2w = (const float*)d_in[33];
  const float* dec_f2b = (const float*)d_in[34];
  const float* cls_w1  = (const float*)d_in[35];
  const float* cls_b1  = (const float*)d_in[36];
  const float* cls_w2  = (const float*)d_in[37];
  const float* cls_b2  = (const float*)d_in[38];
  const float* cls_w3  = (const float*)d_in[39];
  const float* cls_b3  = (const float*)d_in[40];

  float* ws = (float*)d_ws;
  const size_t TE = (size_t)T_ * E_;   // 2M floats
  float* EX = ws + 0 * TE;             // encoder activations / encs
  float* DX = ws + 1 * TE;             // decoder activations
  float* Qb = ws + 2 * TE;
  float* Kb = ws + 3 * TE;
  float* Vb = ws + 4 * TE;
  float* AT = ws + 5 * TE;             // attention output (pre-Wo)
  float* T1 = ws + 6 * TE;
  float* T2 = ws + 7 * TE;
  float* H1 = ws + 2 * TE;             // classifier hidden 1 (2*TE floats)
  float* H2 = ws + 4 * TE;             // classifier hidden 2 (2*TE floats)

  auto gemm = [&](const float* A, const float* W, const float* bias, float* C,
                  int M, int N, int K, int relu) {
    dim3 grid(N / 64, M / 64);
    gemm_f32<<<grid, 256, 0, stream>>>(A, W, bias, C, M, N, K, relu);
  };
  auto attn = [&](const float* Qp, const float* Kp, const float* Vp, float* Op,
                  int causal) {
    const int waves = B_ * NH_ * S_;   // 32768
    attn_kernel<<<waves / 4, 256, 0, stream>>>(Qp, Kp, Vp, Op, causal);
  };
  auto add_ln = [&](const float* Xp, const float* Rp, const float* g,
                    const float* bb, float* Op) {
    add_ln_kernel<<<T_, 256, 0, stream>>>(Xp, Rp, g, bb, Op);
  };

  const int total = T_ * E_;
  add_pe_kernel<<<(total + 255) / 256, 256, 0, stream>>>(x, EX, total);
  add_pe_kernel<<<(total + 255) / 256, 256, 0, stream>>>(y, DX, total);

  // ---------------- encoder ----------------
  for (int i = 0; i < NL_; ++i) {
    const size_t wOff = (size_t)i * EE_;
    const size_t vOff = (size_t)i * E_;
    gemm(EX, enc_wq + wOff, nullptr, Qb, T_, E_, E_, 0);
    gemm(EX, enc_wk + wOff, nullptr, Kb, T_, E_, E_, 0);
    gemm(EX, enc_wv + wOff, nullptr, Vb, T_, E_, E_, 0);
    attn(Qb, Kb, Vb, AT, 0);
    gemm(AT, enc_wo + wOff, enc_bo + vOff, T1, T_, E_, E_, 0);
    add_ln(T1, EX, enc_ln1g + vOff, enc_ln1b + vOff, T2);      // fx
    gemm(T2, enc_f1w + wOff, enc_f1b + vOff, T1, T_, E_, E_, 1);
    gemm(T1, enc_f2w + wOff, enc_f2b + vOff, Qb, T_, E_, E_, 0);
    add_ln(Qb, EX, enc_ln2g + vOff, enc_ln2b + vOff, EX);      // residual to block input
  }
  // EX now holds encs

  // ---------------- decoder ----------------
  for (int i = 0; i < NL_; ++i) {
    const size_t wOff = (size_t)i * EE_;
    const size_t vOff = (size_t)i * E_;
    // masked self-attention
    gemm(DX, dec_wq1 + wOff, nullptr, Qb, T_, E_, E_, 0);
    gemm(DX, dec_wk1 + wOff, nullptr, Kb, T_, E_, E_, 0);
    gemm(DX, dec_wv1 + wOff, nullptr, Vb, T_, E_, E_, 0);
    attn(Qb, Kb, Vb, AT, 1);
    gemm(AT, dec_wo1 + wOff, dec_bo1 + vOff, T1, T_, E_, E_, 0);
    add_ln(T1, DX, dec_ln1g + vOff, dec_ln1b + vOff, T2);      // f1
    // cross-attention (q from f1, k/v from encs)
    gemm(T2, dec_wq2 + wOff, nullptr, Qb, T_, E_, E_, 0);
    gemm(EX, dec_wk2 + wOff, nullptr, Kb, T_, E_, E_, 0);
    gemm(EX, dec_wv2 + wOff, nullptr, Vb, T_, E_, E_, 0);
    attn(Qb, Kb, Vb, AT, 0);
    gemm(AT, dec_wo2 + wOff, dec_bo2 + vOff, T1, T_, E_, E_, 0);
    add_ln(T1, DX, dec_ln2g + vOff, dec_ln2b + vOff, T2);      // f2
    // FFN
    gemm(T2, dec_f1w + wOff, dec_f1b + vOff, T1, T_, E_, E_, 1);
    gemm(T1, dec_f2w + wOff, dec_f2b + vOff, Qb, T_, E_, E_, 0);
    add_ln(Qb, DX, dec_ln3g + vOff, dec_ln3b + vOff, DX);      // residual to block input
  }

  // ---------------- classifier ----------------
  gemm(DX, cls_w1, cls_b1, H1, T_, HC_, E_, 1);
  gemm(H1, cls_w2, cls_b2, H2, T_, HC_, HC_, 1);
  gemm(H2, cls_w3, cls_b3, (float*)d_out, T_, V_, HC_, 0);
}